// Round 5
// baseline (307.324 us; speedup 1.0000x reference)
//
#include <hip/hip_runtime.h>
#include <stdint.h>

typedef _Float16 f16;
typedef _Float16 f16x4 __attribute__((ext_vector_type(4)));
typedef _Float16 f16x8 __attribute__((ext_vector_type(8)));
typedef float f32x4 __attribute__((ext_vector_type(4)));
typedef unsigned long long u64;

#define D_DIM 256
#define K_CB 4096
#define N_ROWS 65536
#define BM 128
#define BN 128
#define N_TILES 32
#define LOSS_OFF 16777216
#define IDS_OFF 16777217
#define MAX_FIX 4096

// workspace layout (bytes)
#define WS_CHI 0            // 4096*256 f16 = 2 MB
#define WS_CN 2097152       // 4096 f32 = 16 KB
#define WS_CNT 2113536      // u32 counter (+pad to 64)
#define WS_ROWS 2113600     // 4096 u32 = 16 KB
#define WS_SLOTS 2129984    // 4096 u64 = 32 KB

// LDS layout (single 1024-thread block, 112 KB):
//   [0, 32768)       B ring: 4 buffers x 8 KB (128 entries x 32 f16, quad-swizzled)
//   [32768, 49152)   cn mirror (4096 f32)  -> reused as mk/lossW scratch after loop
//   [49152, 114688)  A: 128 rows x 256 f16 (-2z), k-major swizzled
#define B_BASE 0
#define CN_BASE 32768
#define A_BASE 49152
#define LDS_BYTES 114688

// direct-to-LDS 16B async copy (per-lane global addr, wave-uniform LDS base + lane*16)
#define GL_LDS(g, s_) __builtin_amdgcn_global_load_lds( \
    (const __attribute__((address_space(1))) void*)(g), \
    (__attribute__((address_space(3))) void*)(s_), 16, 0, 0)

static __device__ __forceinline__ uint32_t f2u(float x) { union { float f; uint32_t u; } c; c.f = x; return c.u; }
static __device__ __forceinline__ float u2f(uint32_t x) { union { float f; uint32_t u; } c; c.u = x; return c.f; }
static __device__ __forceinline__ uint32_t umin_(uint32_t a, uint32_t b) { return a < b ? a : b; }
static __device__ __forceinline__ uint32_t umax_(uint32_t a, uint32_t b) { return a > b ? a : b; }
static __device__ __forceinline__ u64 d2u(double x) { union { double d; u64 u; } c; c.d = x; return c.u; }

// single-instruction 3-input median / min (VOP3, all-VGPR operands)
static __device__ __forceinline__ uint32_t med3u(uint32_t a, uint32_t b, uint32_t c) {
    uint32_t d;
    asm("v_med3_u32 %0, %1, %2, %3" : "=v"(d) : "v"(a), "v"(b), "v"(c));
    return d;
}
static __device__ __forceinline__ uint32_t min3u(uint32_t a, uint32_t b, uint32_t c) {
    uint32_t d;
    asm("v_min3_u32 %0, %1, %2, %3" : "=v"(d) : "v"(a), "v"(b), "v"(c));
    return d;
}

// sorted-top-3 insert: k1<=k2<=k3 invariant.
//   k1' = min(k1,kk); k2' = med3(kk,k1,k2); k3' = med3(kk,k2,k3)
#define INS3(s_, kk_) do { \
    const uint32_t kkv_ = (kk_); \
    const uint32_t n1_ = umin_(k1[s_], kkv_); \
    const uint32_t n2_ = med3u(kkv_, k1[s_], k2[s_]); \
    const uint32_t n3_ = med3u(kkv_, k2[s_], k3[s_]); \
    k1[s_] = n1_; k2[s_] = n2_; k3[s_] = n3_; \
} while (0)

// ---------------- K0: codebook -> f16 hi + fp32 row norms; init cnt/slots/loss ----
__global__ __launch_bounds__(256) void k_prep_cb(const float* __restrict__ cb,
                                                 f16* __restrict__ chi,
                                                 float* __restrict__ cn,
                                                 uint32_t* __restrict__ cnt,
                                                 u64* __restrict__ slots,
                                                 float* __restrict__ loss_slot) {
    const int tid = threadIdx.x;
    const int w = tid >> 6, l = tid & 63;
    const int row = blockIdx.x * 4 + w;            // one wave per codebook row
    const float4 v = ((const float4*)cb)[row * 64 + l];
    f16x4 h4;
    h4[0] = (f16)v.x; h4[1] = (f16)v.y; h4[2] = (f16)v.z; h4[3] = (f16)v.w;
    float ss = v.x * v.x + v.y * v.y + v.z * v.z + v.w * v.w;
#pragma unroll
    for (int m = 32; m >= 1; m >>= 1) ss += __shfl_xor(ss, m);
    ((f16x4*)chi)[row * 64 + l] = h4;
    if (l == 0) cn[row] = ss;
    if (tid < 4) slots[blockIdx.x * 4 + tid] = 0xFFFFFFFFFFFFFFFFull;  // 1024 blocks x 4 = 4096
    if (blockIdx.x == 0 && tid == 0) { *cnt = 0; *loss_slot = 0.0f; }
}

// ---------------- K1: deep-pipelined f16 GEMM + top-3 + rescore ----
// One 1024-thread block per CU (16 waves, 4x4 wave grid, 32x32 out per wave).
// B ring: 4 x 8KB LDS buffers; per step ONE GL_LDS (waves 0..7 only) issued for
// step+3 AFTER the barrier; the barrier waits only `s_waitcnt vmcnt(2)` = the
// load issued 3 steps (~2500 cyc) earlier -> L2 latency fully amortized (T4).
// The loop's ONLY VMEM op is that GL_LDS (cn is mirrored to LDS), so the
// counted vmcnt is exact. Buffer reuse is race-free: writer of buf[(k+3)&3]
// runs after barrier k, which implies all waves finished reading it at k-1.
__global__ __launch_bounds__(1024, 4) void k_main(const float* __restrict__ z,
                                                  const float* __restrict__ cb,
                                                  const f16* __restrict__ chi,
                                                  const float* __restrict__ cn,
                                                  uint32_t* __restrict__ cnt,
                                                  uint32_t* __restrict__ rows,
                                                  float* __restrict__ out) {
    extern __shared__ char smem[];
    const int tid = threadIdx.x;
    const int w = tid >> 6, l = tid & 63;
    const int wm = w >> 2, wn = w & 3;             // 4x4 wave grid, 32x32 sub-tiles
    const int l15 = l & 15, qh = l >> 4;
    const int blk = blockIdx.x;
    const float* ztile = z + (size_t)blk * (BM * D_DIM);

    // ---- B staging constants (pre-swizzled global source -> linear LDS dest) ----
    const int e0 = tid >> 2;                       // threads 0..511 cover entries 0..127
    const int q0 = (tid & 3) ^ ((e0 >> 1) & 3);
    const int offE = e0 * 256 + q0 * 8;

    // ---- prologue: B chunks for steps 0..2 into bufs 0..2 (waves 0..7) ----
    if (w < 8) {
#pragma unroll
        for (int s = 0; s < 3; ++s) {
            const f16* gh = chi + s * 32 + offE;   // tile 0, kc = s
            GL_LDS(gh, smem + B_BASE + s * 8192 + w * 1024);
        }
    }

    // ---- stage cn into LDS (16 KB) ----
    ((float4*)(smem + CN_BASE))[tid] = ((const float4*)cn)[tid];

    // ---- stage A once: fp32 -> f16(-2z), k-major swizzled layout ----
#pragma unroll 4
    for (int p = 0; p < 8; ++p) {
        const int r = p * 16 + w;
        const float4 v = ((const float4*)ztile)[r * 64 + l];
        f16x4 h4;
        h4[0] = (f16)(v.x * -2.0f); h4[1] = (f16)(v.y * -2.0f);
        h4[2] = (f16)(v.z * -2.0f); h4[3] = (f16)(v.w * -2.0f);
        const int kcw = l >> 3, q = (l >> 1) & 3, half = l & 1;
        const int addr = A_BASE + kcw * 8192 + r * 64 + (((q ^ ((r >> 1) & 3))) << 4) + half * 8;
        *(f16x4*)(smem + addr) = h4;
    }

    // ---- A fragment read base (imm offsets kc*8192 + i*1024 on top) ----
    const int ab = A_BASE + wm * 2048 + l15 * 64 + ((qh ^ ((l15 >> 1) & 3)) << 4);

    // ---- B fragment read offsets within an 8KB buffer (buffer sel is imm) ----
    int bcon[2];
#pragma unroll
    for (int j = 0; j < 2; ++j) {
        const int e = wn * 32 + j * 16 + l15;
        bcon[j] = B_BASE + e * 64 + ((qh ^ ((l15 >> 1) & 3)) << 4);
    }
    // per-lane cn LDS address base (advanced by 512 B per tile)
    int cnoff = CN_BASE + (wn * 32 + l15) * 4;

    uint32_t k1[8], k2[8], k3[8];
#pragma unroll
    for (int s = 0; s < 8; ++s) { k1[s] = 0xFFFFFFFFu; k2[s] = 0xFFFFFFFFu; k3[s] = 0xFFFFFFFFu; }

    f32x4 acc[2][2];

    __syncthreads();   // drains ALL vmem (incl. the 3 prologue GL_LDS) -> clean vmcnt ledger

    for (int tile = 0; tile < N_TILES; ++tile) {
        // C-init = cn + 64 -> final acc = cn + 64 - 2*z.c  (positive; key-packable)
        const float cb0 = *(const float*)(smem + cnoff) + 64.0f;
        const float cb1 = *(const float*)(smem + cnoff + 64) + 64.0f;
        cnoff += 512;
        acc[0][0] = (f32x4){cb0, cb0, cb0, cb0};
        acc[1][0] = acc[0][0];
        acc[0][1] = (f32x4){cb1, cb1, cb1, cb1};
        acc[1][1] = acc[0][1];
#pragma unroll
        for (int kc = 0; kc < 8; ++kc) {
            const int step = tile * 8 + kc;
            asm volatile("s_waitcnt vmcnt(2)" ::: "memory");
            __builtin_amdgcn_s_barrier();
            __builtin_amdgcn_sched_barrier(0);
            if (w < 8) {                           // issue load for step+3 (clamped tail)
                int s3 = step + 3; if (s3 > N_TILES * 8 - 1) s3 = N_TILES * 8 - 1;
                const f16* gh = chi + (s3 >> 3) * (BN * D_DIM) + (s3 & 7) * 32 + offE;
                GL_LDS(gh, smem + B_BASE + ((kc + 3) & 3) * 8192 + w * 1024);
            }
            f16x8 ah[2], bh[2];
#pragma unroll
            for (int i = 0; i < 2; ++i)
                ah[i] = *(const f16x8*)(smem + ab + kc * 8192 + i * 1024);
#pragma unroll
            for (int j = 0; j < 2; ++j)
                bh[j] = *(const f16x8*)(smem + bcon[j] + (kc & 3) * 8192);
#pragma unroll
            for (int i = 0; i < 2; ++i)
#pragma unroll
                for (int j = 0; j < 2; ++j)
                    acc[i][j] = __builtin_amdgcn_mfma_f32_16x16x32_f16(ah[i], bh[j], acc[i][j], 0, 0, 0);
        }
        // drain: key = (bits(acc) & ~0xFFF) | col; 3-op sorted-insert per candidate
        const int colb = tile * BN + wn * 32 + l15;
#pragma unroll
        for (int j = 0; j < 2; ++j) {
            const uint32_t col = (uint32_t)(colb + j * 16);
#pragma unroll
            for (int i = 0; i < 2; ++i)
#pragma unroll
                for (int rr = 0; rr < 4; ++rr) {
                    const uint32_t kk = (f2u(acc[i][j][rr]) & 0xFFFFF000u) | col;
                    INS3(i * 4 + rr, kk);
                }
        }
    }
    asm volatile("s_waitcnt vmcnt(0)" ::: "memory");  // retire tail GL_LDS before exit path

    // ---- merge sorted triples across the 16 column-lanes of each row ----
#pragma unroll
    for (int s = 0; s < 8; ++s) {
        uint32_t a1 = k1[s], a2 = k2[s], a3 = k3[s];
#pragma unroll
        for (int m = 1; m <= 8; m <<= 1) {
            const uint32_t b1 = (uint32_t)__shfl_xor((int)a1, m);
            const uint32_t b2 = (uint32_t)__shfl_xor((int)a2, m);
            const uint32_t b3 = (uint32_t)__shfl_xor((int)a3, m);
            const uint32_t r1 = umin_(a1, b1);
            const uint32_t r2 = min3u(a2, b2, umax_(a1, b1));
            const uint32_t r3 = min3u(umax_(a1, b2), umax_(a2, b1), umin_(a3, b3));
            a1 = r1; a2 = r2; a3 = r3;
        }
        k1[s] = a1; k2[s] = a2; k3[s] = a3;
    }
    __syncthreads();                               // cn region reusable now (B ring left alone)
    uint32_t* mk = (uint32_t*)(smem + CN_BASE);    // mk1[128] | mk2[128] | mk3[128]
    double* lossW = (double*)(smem + CN_BASE + 1536);
    if (wn == 0 && l15 == 0) {
#pragma unroll
        for (int s = 0; s < 8; ++s) {
            const int row = wm * 32 + (s >> 2) * 16 + qh * 4 + (s & 3);
            mk[row] = k1[s]; mk[128 + row] = k2[s]; mk[256 + row] = k3[s];
        }
    }
#pragma unroll
    for (int mw = 1; mw < 4; ++mw) {
        __syncthreads();
        if (wn == mw && l15 == 0) {
#pragma unroll
            for (int s = 0; s < 8; ++s) {
                const int row = wm * 32 + (s >> 2) * 16 + qh * 4 + (s & 3);
                const uint32_t b1 = mk[row], b2 = mk[128 + row], b3 = mk[256 + row];
                mk[row] = umin_(k1[s], b1);
                mk[128 + row] = min3u(k2[s], b2, umax_(k1[s], b1));
                mk[256 + row] = min3u(umax_(k1[s], b2), umax_(k2[s], b1), umin_(k3[s], b3));
            }
        }
    }
    __syncthreads();

    // ---- gather + exact f64 rescore of top-2 + certification + loss ----
    double lossAcc = 0.0;
    for (int it = 0; it < 8; ++it) {
        const int row = it * 16 + w;               // one wave per row
        const uint32_t K1 = mk[row], K2 = mk[128 + row], K3 = mk[256 + row];
        const int col1 = (int)(K1 & 4095u), col2 = (int)(K2 & 4095u);
        const float4 c1 = ((const float4*)cb)[col1 * 64 + l];
        const float4 c2 = ((const float4*)cb)[col2 * 64 + l];
        const float4 z4 = ((const float4*)ztile)[row * 64 + l];
        double e1, e2;
        {
            const double dx1 = (double)c1.x - z4.x, dy1 = (double)c1.y - z4.y;
            const double dz1 = (double)c1.z - z4.z, dw1 = (double)c1.w - z4.w;
            e1 = dx1 * dx1 + dy1 * dy1 + dz1 * dz1 + dw1 * dw1;
            const double dx2 = (double)c2.x - z4.x, dy2 = (double)c2.y - z4.y;
            const double dz2 = (double)c2.z - z4.z, dw2 = (double)c2.w - z4.w;
            e2 = dx2 * dx2 + dy2 * dy2 + dz2 * dz2 + dw2 * dw2;
        }
        float zn2 = z4.x * z4.x + z4.y * z4.y + z4.z * z4.z + z4.w * z4.w;
#pragma unroll
        for (int m = 32; m >= 1; m >>= 1) {
            e1 += __shfl_xor(e1, m);
            e2 += __shfl_xor(e2, m);
            zn2 += __shfl_xor(zn2, m);
        }
        const bool take1 = (e1 < e2) || (e1 == e2 && col1 <= col2);
        const float4 cw = take1 ? c1 : c2;
        ((float4*)out)[(blk * BM + row) * 64 + l] = cw;
        if (l == 0) {
            const int colw = take1 ? col1 : col2;
            const double ew = take1 ? e1 : e2;
            out[IDS_OFF + blk * BM + row] = (float)colw;
            lossAcc += ew;
            // key = cn - 2M + 64 -> d2 lower bound of 3rd-best = key + zn - 64
            const float d3 = u2f(K3 & 0xFFFFF000u) + zn2 - 64.0f;
            const float eps = 0.006f * sqrtf(zn2) + 0.01f;
            if (!((float)ew < d3 - eps)) {
                const uint32_t e = atomicAdd(cnt, 1u);
                if (e < MAX_FIX) rows[e] = (uint32_t)(blk * BM + row);
            }
        }
    }
    if (l == 0) lossW[w] = lossAcc;
    __syncthreads();
    if (tid == 0) {
        double tot = 0.0;
#pragma unroll
        for (int i = 0; i < 16; ++i) tot += lossW[i];
        atomicAdd(out + LOSS_OFF, (float)(tot * (1.25 / 16777216.0)));
    }
}

// ---------------- K2a: parallel exact scan for flagged rows (16 blocks per row) ----
__global__ __launch_bounds__(256) void k_fix_scan(const float* __restrict__ z,
                                                  const float* __restrict__ cb,
                                                  const uint32_t* __restrict__ cnt,
                                                  const uint32_t* __restrict__ rows,
                                                  u64* __restrict__ slots) {
    __shared__ float zrow[256];
    __shared__ u64 wmin[4];
    const int tid = threadIdx.x;
    const int w = tid >> 6, l = tid & 63;
    const int chunk = blockIdx.x & 15;
    uint32_t n = *cnt; if (n > MAX_FIX) n = MAX_FIX;
    for (uint32_t e = blockIdx.x >> 4; e < n; e += 64) {
        const int row = (int)rows[e];
        __syncthreads();                           // protect zrow across iterations
        if (tid < 64) ((float4*)zrow)[tid] = ((const float4*)z)[row * 64 + tid];
        __syncthreads();
        const int c = chunk * 256 + tid;
        const float4* crow = (const float4*)(cb + (size_t)c * 256);
        double s = 0.0;
        for (int q = 0; q < 64; ++q) {
            const float4 cv = crow[q];
            const float4 zv = ((const float4*)zrow)[q];
            const double dx = (double)cv.x - zv.x, dy = (double)cv.y - zv.y;
            const double dz = (double)cv.z - zv.z, dw = (double)cv.w - zv.w;
            s += dx * dx + dy * dy + dz * dz + dw * dw;
        }
        u64 key = (d2u(s) & 0xFFFFFFFFFFFFF000ull) | (u64)c;  // d2 desc-trunc + col tiebreak
#pragma unroll
        for (int m = 32; m >= 1; m >>= 1) {
            const u64 o = __shfl_xor(key, m);
            if (o < key) key = o;
        }
        if (l == 0) wmin[w] = key;
        __syncthreads();
        if (tid == 0) {
            u64 k = wmin[0];
            if (wmin[1] < k) k = wmin[1];
            if (wmin[2] < k) k = wmin[2];
            if (wmin[3] < k) k = wmin[3];
            atomicMin(&slots[e], k);
        }
    }
}

// ---------------- K2b: patch ids / z_q / loss for flagged rows ----
__global__ __launch_bounds__(256) void k_fix_patch(const float* __restrict__ z,
                                                   const float* __restrict__ cb,
                                                   const uint32_t* __restrict__ cnt,
                                                   const uint32_t* __restrict__ rows,
                                                   const u64* __restrict__ slots,
                                                   float* __restrict__ out) {
    const int tid = threadIdx.x;
    uint32_t n = *cnt; if (n > MAX_FIX) n = MAX_FIX;
    for (uint32_t e = blockIdx.x; e < n; e += 256) {
        const int row = (int)rows[e];
        const int newc = (int)(slots[e] & 4095ull);
        const int oldc = (int)out[IDS_OFF + row];
        if (newc == oldc) continue;                // uniform across block
        double dOld = 0.0, dNew = 0.0;
        if (tid < 64) {
            const float4 zv = ((const float4*)z)[row * 64 + tid];
            const float4 co = ((const float4*)cb)[oldc * 64 + tid];
            const float4 cn4 = ((const float4*)cb)[newc * 64 + tid];
            const double ax = (double)co.x - zv.x, ay = (double)co.y - zv.y;
            const double az = (double)co.z - zv.z, aw = (double)co.w - zv.w;
            dOld = ax * ax + ay * ay + az * az + aw * aw;
            const double bx = (double)cn4.x - zv.x, by = (double)cn4.y - zv.y;
            const double bz = (double)cn4.z - zv.z, bw = (double)cn4.w - zv.w;
            dNew = bx * bx + by * by + bz * bz + bw * bw;
            ((float4*)out)[row * 64 + tid] = cn4;  // patch z_q
        }
#pragma unroll
        for (int m = 32; m >= 1; m >>= 1) {
            dOld += __shfl_xor(dOld, m);
            dNew += __shfl_xor(dNew, m);
        }
        if (tid == 0) {
            out[IDS_OFF + row] = (float)newc;
            atomicAdd(out + LOSS_OFF, (float)((dNew - dOld) * (1.25 / 16777216.0)));
        }
    }
}

extern "C" void kernel_launch(void* const* d_in, const int* in_sizes, int n_in,
                              void* d_out, int out_size, void* d_ws, size_t ws_size,
                              hipStream_t stream) {
    (void)in_sizes; (void)n_in; (void)out_size; (void)ws_size;
    const float* z = (const float*)d_in[0];
    const float* cb = (const float*)d_in[1];
    float* out = (float*)d_out;
    char* ws = (char*)d_ws;
    f16* chi = (f16*)(ws + WS_CHI);
    float* cn = (float*)(ws + WS_CN);
    uint32_t* cnt = (uint32_t*)(ws + WS_CNT);
    uint32_t* rows = (uint32_t*)(ws + WS_ROWS);
    u64* slots = (u64*)(ws + WS_SLOTS);

    hipFuncSetAttribute((const void*)k_main,
                        hipFuncAttributeMaxDynamicSharedMemorySize, LDS_BYTES);

    k_prep_cb<<<K_CB / 4, 256, 0, stream>>>(cb, chi, cn, cnt, slots, out + LOSS_OFF);
    k_main<<<N_ROWS / BM, 1024, LDS_BYTES, stream>>>(z, cb, chi, cn, cnt, rows, out);
    k_fix_scan<<<1024, 256, 0, stream>>>(z, cb, cnt, rows, slots);
    k_fix_patch<<<256, 256, 0, stream>>>(z, cb, cnt, rows, slots, out);
}

// Round 6
// 296.013 us; speedup vs baseline: 1.0382x; 1.0382x over previous
//
#include <hip/hip_runtime.h>
#include <stdint.h>

typedef _Float16 f16;
typedef _Float16 f16x4 __attribute__((ext_vector_type(4)));
typedef _Float16 f16x8 __attribute__((ext_vector_type(8)));
typedef float f32x4 __attribute__((ext_vector_type(4)));
typedef unsigned long long u64;

#define D_DIM 256
#define K_CB 4096
#define N_ROWS 65536
#define BM 128
#define BN 256
#define N_TILES 16
#define N_STEPS 128
#define LOSS_OFF 16777216
#define IDS_OFF 16777217
#define MAX_FIX 4096

// workspace layout (bytes)
#define WS_CHI 0            // 4096*256 f16 = 2 MB
#define WS_CN 2097152       // 4096 f32 = 16 KB
#define WS_CNT 2113536      // u32 counter (+pad to 64)
#define WS_ROWS 2113600     // 4096 u32 = 16 KB
#define WS_SLOTS 2129984    // 4096 u64 = 32 KB

// LDS layout (one 512-thread block, 144 KB):
//   [0, 65536)        A: 128 rows x 256 f16 (-2z), k-major swizzled (imm-addressable)
//   [65536, 131072)   B ring: 4 buffers x 16 KB (256 entries x 32 f16, quad-swizzled)
//   [131072, 147456)  cn mirror (4096 f32) -> reused as mk/lossW scratch after loop
#define A_BASE 0
#define B_BASE 65536
#define CN_BASE 131072
#define LDS_BYTES 147456

// direct-to-LDS 16B async copy (per-lane global addr, wave-uniform LDS base + lane*16)
#define GL_LDS(g, s_) __builtin_amdgcn_global_load_lds( \
    (const __attribute__((address_space(1))) void*)(g), \
    (__attribute__((address_space(3))) void*)(s_), 16, 0, 0)

static __device__ __forceinline__ uint32_t f2u(float x) { union { float f; uint32_t u; } c; c.f = x; return c.u; }
static __device__ __forceinline__ float u2f(uint32_t x) { union { float f; uint32_t u; } c; c.u = x; return c.f; }
static __device__ __forceinline__ uint32_t umin_(uint32_t a, uint32_t b) { return a < b ? a : b; }
static __device__ __forceinline__ uint32_t umax_(uint32_t a, uint32_t b) { return a > b ? a : b; }
static __device__ __forceinline__ u64 d2u(double x) { union { double d; u64 u; } c; c.d = x; return c.u; }

// single-instruction 3-input median / min (VOP3, all-VGPR operands)
static __device__ __forceinline__ uint32_t med3u(uint32_t a, uint32_t b, uint32_t c) {
    uint32_t d;
    asm("v_med3_u32 %0, %1, %2, %3" : "=v"(d) : "v"(a), "v"(b), "v"(c));
    return d;
}
static __device__ __forceinline__ uint32_t min3u(uint32_t a, uint32_t b, uint32_t c) {
    uint32_t d;
    asm("v_min3_u32 %0, %1, %2, %3" : "=v"(d) : "v"(a), "v"(b), "v"(c));
    return d;
}

// sorted-top-3 insert: k1<=k2<=k3 invariant.
//   k1' = min(k1,kk); k2' = med3(kk,k1,k2); k3' = med3(kk,k2,k3)
#define INS3(s_, kk_) do { \
    const uint32_t kkv_ = (kk_); \
    const uint32_t n1_ = umin_(k1[s_], kkv_); \
    const uint32_t n2_ = med3u(kkv_, k1[s_], k2[s_]); \
    const uint32_t n3_ = med3u(kkv_, k2[s_], k3[s_]); \
    k1[s_] = n1_; k2[s_] = n2_; k3[s_] = n3_; \
} while (0)

// ---------------- K0: codebook -> f16 hi + fp32 row norms; init cnt/slots/loss ----
__global__ __launch_bounds__(256) void k_prep_cb(const float* __restrict__ cb,
                                                 f16* __restrict__ chi,
                                                 float* __restrict__ cn,
                                                 uint32_t* __restrict__ cnt,
                                                 u64* __restrict__ slots,
                                                 float* __restrict__ loss_slot) {
    const int tid = threadIdx.x;
    const int w = tid >> 6, l = tid & 63;
    const int row = blockIdx.x * 4 + w;            // one wave per codebook row
    const float4 v = ((const float4*)cb)[row * 64 + l];
    f16x4 h4;
    h4[0] = (f16)v.x; h4[1] = (f16)v.y; h4[2] = (f16)v.z; h4[3] = (f16)v.w;
    float ss = v.x * v.x + v.y * v.y + v.z * v.z + v.w * v.w;
#pragma unroll
    for (int m = 32; m >= 1; m >>= 1) ss += __shfl_xor(ss, m);
    ((f16x4*)chi)[row * 64 + l] = h4;
    if (l == 0) cn[row] = ss;
    if (tid < 4) slots[blockIdx.x * 4 + tid] = 0xFFFFFFFFFFFFFFFFull;  // 1024 blocks x 4 = 4096
    if (blockIdx.x == 0 && tid == 0) { *cnt = 0; *loss_slot = 0.0f; }
}

// ---------------- K1: LDS-traffic-minimized pipelined f16 GEMM + top-3 + rescore ----
// 512 threads / 8 waves, 2x4 wave grid, 64x64 output per wave (acc[4][4]).
// Per step (BK=32, BN=256): per CU 64 KB ds_read + 16 KB stage vs 128 MFMA — the
// smallest LDS-bytes/MFMA wave decomposition that fits registers (R5 post-mortem:
// kernel is LDS-port-bound, not occupancy- or vmcnt-latency-bound).
// Convoy breaker: cur/nxt fragment register double-buffer. MFMA(k) consumes frags
// read during step k-1; step k's 8 ds_reads (for k+1) issue BEFORE the MFMA cluster
// and retire under it (compiler emits lgkmcnt(8)). Requires B(k+1) already in LDS:
// ring-4 B with depth-3 GL_LDS (issue pair(k+3) at step k; vmcnt(2) at barrier k
// waits only pair(k+1), issued 2 steps / ~2000 cyc earlier).
__global__ __launch_bounds__(512, 2) void k_main(const float* __restrict__ z,
                                                 const float* __restrict__ cb,
                                                 const f16* __restrict__ chi,
                                                 const float* __restrict__ cn,
                                                 uint32_t* __restrict__ cnt,
                                                 uint32_t* __restrict__ rows,
                                                 float* __restrict__ out) {
    extern __shared__ char smem[];
    const int tid = threadIdx.x;
    const int w = tid >> 6, l = tid & 63;
    const int wm = w >> 2, wn = w & 3;             // 2x4 wave grid, 64x64 sub-tiles
    const int l15 = l & 15, qh = l >> 4;
    const int blk = blockIdx.x;
    const float* ztile = z + (size_t)blk * (BM * D_DIM);

    // ---- B staging constants: 16 KB/step, 2 GL_LDS per thread ----
    // instruction u of wave w covers entries (u*8+w)*16 + (l>>2), quad (l&3)^swz
    const int e_lo = (w << 4) + (l >> 2);
    const int swq = ((l & 3) ^ ((l >> 3) & 3)) << 3;     // source quad pre-swizzle (f16 units)
    const int offE0 = e_lo * 256 + swq;
    const int offE1 = offE0 + 32768;                     // +128 entries
    const int stg0 = w * 1024;                           // LDS: + B_BASE + buf*16384
    const int stg1 = stg0 + 8192;

    // ---- prologue: B chunks for steps 0..2 into bufs 0..2 (overlap A staging) ----
#pragma unroll
    for (int s = 0; s < 3; ++s) {
        const f16* gh = chi + s * 32;              // tile 0, nk = s
        GL_LDS(gh + offE0, smem + B_BASE + s * 16384 + stg0);
        GL_LDS(gh + offE1, smem + B_BASE + s * 16384 + stg1);
    }

    // ---- stage cn into LDS (16 KB) ----
    ((float4*)(smem + CN_BASE))[tid] = ((const float4*)cn)[tid];
    ((float4*)(smem + CN_BASE))[tid + 512] = ((const float4*)cn)[tid + 512];

    // ---- stage A once: fp32 -> f16(-2z), k-major swizzled layout ----
#pragma unroll 4
    for (int p = 0; p < 16; ++p) {
        const int r = p * 8 + w;
        const float4 v = ((const float4*)ztile)[r * 64 + l];
        f16x4 h4;
        h4[0] = (f16)(v.x * -2.0f); h4[1] = (f16)(v.y * -2.0f);
        h4[2] = (f16)(v.z * -2.0f); h4[3] = (f16)(v.w * -2.0f);
        const int kcw = l >> 3, q = (l >> 1) & 3, half = l & 1;
        const int addr = A_BASE + kcw * 8192 + r * 64 + (((q ^ ((r >> 1) & 3))) << 4) + half * 8;
        *(f16x4*)(smem + addr) = h4;
    }

    // ---- fragment read bases (compile-time imm on top) ----
    const int ab = A_BASE + wm * 4096 + l15 * 64 + ((qh ^ ((l15 >> 1) & 3)) << 4);
    const int bb0 = B_BASE + wn * 4096 + l15 * 64 + ((qh ^ ((l15 >> 1) & 3)) << 4);

    uint32_t k1[16], k2[16], k3[16];
#pragma unroll
    for (int s = 0; s < 16; ++s) { k1[s] = 0xFFFFFFFFu; k2[s] = 0xFFFFFFFFu; k3[s] = 0xFFFFFFFFu; }

    f32x4 acc[4][4];
    f16x8 pA[4], pB[4], qA[4], qB[4];              // cur/nxt frag sets (static indexing)

    __syncthreads();   // A/B0..2/cn staged, all counters drained -> clean vmcnt ledger

    // pre-read frags(0) into p-set
#pragma unroll
    for (int i = 0; i < 4; ++i) pA[i] = *(const f16x8*)(smem + ab + i * 1024);
#pragma unroll
    for (int j = 0; j < 4; ++j) pB[j] = *(const f16x8*)(smem + bb0 + j * 1024);

// one K-step: barrier (counted vmcnt), stage step+3, read frags(step+1) into N-set,
// MFMA with C-set. Buffer/offset selectors all compile-time per kc.
#define K_STEP(kc_, CA, CB, NA, NB) do { \
    asm volatile("s_waitcnt vmcnt(2)" ::: "memory"); \
    __builtin_amdgcn_s_barrier(); \
    __builtin_amdgcn_sched_barrier(0); \
    { int s3 = tile * 8 + (kc_) + 3; if (s3 > N_STEPS - 1) s3 = N_STEPS - 1; \
      const f16* gh_ = chi + (s3 >> 3) * (BN * D_DIM) + (s3 & 7) * 32; \
      char* bb_ = smem + B_BASE + (((kc_) + 3) & 3) * 16384; \
      GL_LDS(gh_ + offE0, bb_ + stg0); \
      GL_LDS(gh_ + offE1, bb_ + stg1); } \
    _Pragma("unroll") for (int i = 0; i < 4; ++i) \
        NA[i] = *(const f16x8*)(smem + ab + (((kc_) + 1) & 7) * 8192 + i * 1024); \
    _Pragma("unroll") for (int j = 0; j < 4; ++j) \
        NB[j] = *(const f16x8*)(smem + bb0 + (((kc_) + 1) & 3) * 16384 + j * 1024); \
    _Pragma("unroll") for (int i = 0; i < 4; ++i) \
        _Pragma("unroll") for (int j = 0; j < 4; ++j) \
            acc[i][j] = __builtin_amdgcn_mfma_f32_16x16x32_f16(CA[i], CB[j], acc[i][j], 0, 0, 0); \
} while (0)

    for (int tile = 0; tile < N_TILES; ++tile) {
        // C-init = cn + 64 -> final acc = cn + 64 - 2*z.c  (positive; key-packable)
        const int cnb = CN_BASE + tile * 1024 + wn * 256 + l15 * 4;
#pragma unroll
        for (int j = 0; j < 4; ++j) {
            const float base = *(const float*)(smem + cnb + j * 64) + 64.0f;
#pragma unroll
            for (int i = 0; i < 4; ++i) acc[i][j] = (f32x4){base, base, base, base};
        }
        K_STEP(0, pA, pB, qA, qB);
        K_STEP(1, qA, qB, pA, pB);
        K_STEP(2, pA, pB, qA, qB);
        K_STEP(3, qA, qB, pA, pB);
        K_STEP(4, pA, pB, qA, qB);
        K_STEP(5, qA, qB, pA, pB);
        K_STEP(6, pA, pB, qA, qB);
        K_STEP(7, qA, qB, pA, pB);
        // drain: key = (bits(acc) & ~0xFFF) | col; 3-op sorted-insert per candidate
        const int colb = tile * BN + wn * 64 + l15;
#pragma unroll
        for (int j = 0; j < 4; ++j) {
            const uint32_t col = (uint32_t)(colb + j * 16);
#pragma unroll
            for (int i = 0; i < 4; ++i)
#pragma unroll
                for (int rr = 0; rr < 4; ++rr) {
                    const uint32_t kk = (f2u(acc[i][j][rr]) & 0xFFFFF000u) | col;
                    INS3(i * 4 + rr, kk);
                }
        }
    }
#undef K_STEP
    asm volatile("s_waitcnt vmcnt(0)" ::: "memory");  // retire tail GL_LDS

    // ---- merge sorted triples across the 16 column-lanes of each row ----
#pragma unroll
    for (int s = 0; s < 16; ++s) {
        uint32_t a1 = k1[s], a2 = k2[s], a3 = k3[s];
#pragma unroll
        for (int m = 1; m <= 8; m <<= 1) {
            const uint32_t b1 = (uint32_t)__shfl_xor((int)a1, m);
            const uint32_t b2 = (uint32_t)__shfl_xor((int)a2, m);
            const uint32_t b3 = (uint32_t)__shfl_xor((int)a3, m);
            const uint32_t r1 = umin_(a1, b1);
            const uint32_t r2 = min3u(a2, b2, umax_(a1, b1));
            const uint32_t r3 = min3u(umax_(a1, b2), umax_(a2, b1), umin_(a3, b3));
            a1 = r1; a2 = r2; a3 = r3;
        }
        k1[s] = a1; k2[s] = a2; k3[s] = a3;
    }
    __syncthreads();                               // cn region reusable now
    uint32_t* mk = (uint32_t*)(smem + CN_BASE);    // mk1[128] | mk2[128] | mk3[128]
    double* lossW = (double*)(smem + CN_BASE + 1536);
    if (wn == 0 && l15 == 0) {
#pragma unroll
        for (int s = 0; s < 16; ++s) {
            const int row = wm * 64 + (s >> 2) * 16 + qh * 4 + (s & 3);
            mk[row] = k1[s]; mk[128 + row] = k2[s]; mk[256 + row] = k3[s];
        }
    }
#pragma unroll
    for (int mw = 1; mw < 4; ++mw) {
        __syncthreads();
        if (wn == mw && l15 == 0) {
#pragma unroll
            for (int s = 0; s < 16; ++s) {
                const int row = wm * 64 + (s >> 2) * 16 + qh * 4 + (s & 3);
                const uint32_t b1 = mk[row], b2 = mk[128 + row], b3 = mk[256 + row];
                mk[row] = umin_(k1[s], b1);
                mk[128 + row] = min3u(k2[s], b2, umax_(k1[s], b1));
                mk[256 + row] = min3u(umax_(k1[s], b2), umax_(k2[s], b1), umin_(k3[s], b3));
            }
        }
    }
    __syncthreads();

    // ---- gather + exact f64 rescore of top-2 + certification + loss ----
    double lossAcc = 0.0;
    for (int it = 0; it < 16; ++it) {
        const int row = it * 8 + w;                // one wave per row
        const uint32_t K1 = mk[row], K2 = mk[128 + row], K3 = mk[256 + row];
        const int col1 = (int)(K1 & 4095u), col2 = (int)(K2 & 4095u);
        const float4 c1 = ((const float4*)cb)[col1 * 64 + l];
        const float4 c2 = ((const float4*)cb)[col2 * 64 + l];
        const float4 z4 = ((const float4*)ztile)[row * 64 + l];
        double e1, e2;
        {
            const double dx1 = (double)c1.x - z4.x, dy1 = (double)c1.y - z4.y;
            const double dz1 = (double)c1.z - z4.z, dw1 = (double)c1.w - z4.w;
            e1 = dx1 * dx1 + dy1 * dy1 + dz1 * dz1 + dw1 * dw1;
            const double dx2 = (double)c2.x - z4.x, dy2 = (double)c2.y - z4.y;
            const double dz2 = (double)c2.z - z4.z, dw2 = (double)c2.w - z4.w;
            e2 = dx2 * dx2 + dy2 * dy2 + dz2 * dz2 + dw2 * dw2;
        }
        float zn2 = z4.x * z4.x + z4.y * z4.y + z4.z * z4.z + z4.w * z4.w;
#pragma unroll
        for (int m = 32; m >= 1; m >>= 1) {
            e1 += __shfl_xor(e1, m);
            e2 += __shfl_xor(e2, m);
            zn2 += __shfl_xor(zn2, m);
        }
        const bool take1 = (e1 < e2) || (e1 == e2 && col1 <= col2);
        const float4 cw = take1 ? c1 : c2;
        ((float4*)out)[(blk * BM + row) * 64 + l] = cw;
        if (l == 0) {
            const int colw = take1 ? col1 : col2;
            const double ew = take1 ? e1 : e2;
            out[IDS_OFF + blk * BM + row] = (float)colw;
            lossAcc += ew;
            // key = cn - 2M + 64 -> d2 lower bound of 3rd-best = key + zn - 64
            const float d3 = u2f(K3 & 0xFFFFF000u) + zn2 - 64.0f;
            const float eps = 0.006f * sqrtf(zn2) + 0.01f;
            if (!((float)ew < d3 - eps)) {
                const uint32_t e = atomicAdd(cnt, 1u);
                if (e < MAX_FIX) rows[e] = (uint32_t)(blk * BM + row);
            }
        }
    }
    if (l == 0) lossW[w] = lossAcc;
    __syncthreads();
    if (tid == 0) {
        double tot = 0.0;
#pragma unroll
        for (int i = 0; i < 8; ++i) tot += lossW[i];
        atomicAdd(out + LOSS_OFF, (float)(tot * (1.25 / 16777216.0)));
    }
}

// ---------------- K2a: parallel exact scan for flagged rows (16 blocks per row) ----
__global__ __launch_bounds__(256) void k_fix_scan(const float* __restrict__ z,
                                                  const float* __restrict__ cb,
                                                  const uint32_t* __restrict__ cnt,
                                                  const uint32_t* __restrict__ rows,
                                                  u64* __restrict__ slots) {
    __shared__ float zrow[256];
    __shared__ u64 wmin[4];
    const int tid = threadIdx.x;
    const int w = tid >> 6, l = tid & 63;
    const int chunk = blockIdx.x & 15;
    uint32_t n = *cnt; if (n > MAX_FIX) n = MAX_FIX;
    for (uint32_t e = blockIdx.x >> 4; e < n; e += 64) {
        const int row = (int)rows[e];
        __syncthreads();                           // protect zrow across iterations
        if (tid < 64) ((float4*)zrow)[tid] = ((const float4*)z)[row * 64 + tid];
        __syncthreads();
        const int c = chunk * 256 + tid;
        const float4* crow = (const float4*)(cb + (size_t)c * 256);
        double s = 0.0;
        for (int q = 0; q < 64; ++q) {
            const float4 cv = crow[q];
            const float4 zv = ((const float4*)zrow)[q];
            const double dx = (double)cv.x - zv.x, dy = (double)cv.y - zv.y;
            const double dz = (double)cv.z - zv.z, dw = (double)cv.w - zv.w;
            s += dx * dx + dy * dy + dz * dz + dw * dw;
        }
        u64 key = (d2u(s) & 0xFFFFFFFFFFFFF000ull) | (u64)c;  // d2 desc-trunc + col tiebreak
#pragma unroll
        for (int m = 32; m >= 1; m >>= 1) {
            const u64 o = __shfl_xor(key, m);
            if (o < key) key = o;
        }
        if (l == 0) wmin[w] = key;
        __syncthreads();
        if (tid == 0) {
            u64 k = wmin[0];
            if (wmin[1] < k) k = wmin[1];
            if (wmin[2] < k) k = wmin[2];
            if (wmin[3] < k) k = wmin[3];
            atomicMin(&slots[e], k);
        }
    }
}

// ---------------- K2b: patch ids / z_q / loss for flagged rows ----
__global__ __launch_bounds__(256) void k_fix_patch(const float* __restrict__ z,
                                                   const float* __restrict__ cb,
                                                   const uint32_t* __restrict__ cnt,
                                                   const uint32_t* __restrict__ rows,
                                                   const u64* __restrict__ slots,
                                                   float* __restrict__ out) {
    const int tid = threadIdx.x;
    uint32_t n = *cnt; if (n > MAX_FIX) n = MAX_FIX;
    for (uint32_t e = blockIdx.x; e < n; e += 256) {
        const int row = (int)rows[e];
        const int newc = (int)(slots[e] & 4095ull);
        const int oldc = (int)out[IDS_OFF + row];
        if (newc == oldc) continue;                // uniform across block
        double dOld = 0.0, dNew = 0.0;
        if (tid < 64) {
            const float4 zv = ((const float4*)z)[row * 64 + tid];
            const float4 co = ((const float4*)cb)[oldc * 64 + tid];
            const float4 cn4 = ((const float4*)cb)[newc * 64 + tid];
            const double ax = (double)co.x - zv.x, ay = (double)co.y - zv.y;
            const double az = (double)co.z - zv.z, aw = (double)co.w - zv.w;
            dOld = ax * ax + ay * ay + az * az + aw * aw;
            const double bx = (double)cn4.x - zv.x, by = (double)cn4.y - zv.y;
            const double bz = (double)cn4.z - zv.z, bw = (double)cn4.w - zv.w;
            dNew = bx * bx + by * by + bz * bz + bw * bw;
            ((float4*)out)[row * 64 + tid] = cn4;  // patch z_q
        }
#pragma unroll
        for (int m = 32; m >= 1; m >>= 1) {
            dOld += __shfl_xor(dOld, m);
            dNew += __shfl_xor(dNew, m);
        }
        if (tid == 0) {
            out[IDS_OFF + row] = (float)newc;
            atomicAdd(out + LOSS_OFF, (float)((dNew - dOld) * (1.25 / 16777216.0)));
        }
    }
}

extern "C" void kernel_launch(void* const* d_in, const int* in_sizes, int n_in,
                              void* d_out, int out_size, void* d_ws, size_t ws_size,
                              hipStream_t stream) {
    (void)in_sizes; (void)n_in; (void)out_size; (void)ws_size;
    const float* z = (const float*)d_in[0];
    const float* cb = (const float*)d_in[1];
    float* out = (float*)d_out;
    char* ws = (char*)d_ws;
    f16* chi = (f16*)(ws + WS_CHI);
    float* cn = (float*)(ws + WS_CN);
    uint32_t* cnt = (uint32_t*)(ws + WS_CNT);
    uint32_t* rows = (uint32_t*)(ws + WS_ROWS);
    u64* slots = (u64*)(ws + WS_SLOTS);

    hipFuncSetAttribute((const void*)k_main,
                        hipFuncAttributeMaxDynamicSharedMemorySize, LDS_BYTES);

    k_prep_cb<<<K_CB / 4, 256, 0, stream>>>(cb, chi, cn, cnt, slots, out + LOSS_OFF);
    k_main<<<N_ROWS / BM, 512, LDS_BYTES, stream>>>(z, cb, chi, cn, cnt, rows, out);
    k_fix_scan<<<1024, 256, 0, stream>>>(z, cb, cnt, rows, slots);
    k_fix_patch<<<256, 256, 0, stream>>>(z, cb, cnt, rows, slots, out);
}